// Round 14
// baseline (914.116 us; speedup 1.0000x reference)
//
#include <hip/hip_runtime.h>

#define N_DIM 256
#define BATCH 64
#define BS 64          // one wave per block; lane t owns columns/rows 4t..4t+3
#define SCALE 4096.0f  // fixed-point scale 2^12
#define KBIAS (1 << 20) // key bias: keeps biased distances positive (stale-u)

#define DPP_MINU(x, ctrl) do {                                                 \
    unsigned _s = (unsigned)__builtin_amdgcn_update_dpp((int)(x), (int)(x),    \
                                                        (ctrl), 0xf, 0xf, false); \
    (x) = ((x) < _s) ? (x) : _s;                                               \
} while (0)

// Hybrid full-wave u32 min: 4 DPP stages reduce within each 16-lane row
// (result in lanes 15/31/47/63), then 4 independent readlanes + scalar mins.
__device__ __forceinline__ unsigned wave_min_u32(unsigned x) {
    DPP_MINU(x, 0x111);  // row_shr:1
    DPP_MINU(x, 0x112);  // row_shr:2
    DPP_MINU(x, 0x114);  // row_shr:4
    DPP_MINU(x, 0x118);  // row_shr:8
    const unsigned a = (unsigned)__builtin_amdgcn_readlane((int)x, 15);
    const unsigned b = (unsigned)__builtin_amdgcn_readlane((int)x, 31);
    const unsigned c = (unsigned)__builtin_amdgcn_readlane((int)x, 47);
    const unsigned d = (unsigned)__builtin_amdgcn_readlane((int)x, 63);
    const unsigned ab = (a < b) ? a : b;
    const unsigned cd = (c < d) ? c : d;
    return (ab < cd) ? ab : cd;
}

// uniform-index lookup from 4 per-lane mirror regs: 2 selects + 1 readlane
__device__ __forceinline__ int rd4_i(int x0, int x1, int x2, int x3, int idx) {
    const int sel = idx & 3, src = idx >> 2;
    int ab = (sel & 1) ? x1 : x0;
    int cd = (sel & 1) ? x3 : x2;
    int vv = (sel & 2) ? cd : ab;
    return __builtin_amdgcn_readlane(vv, src);
}

// owner-lane mirror update (idx wave-uniform)
#define SET4(x0, x1, x2, x3, idx, val) do {                                    \
    const int _sel = (idx) & 3;                                                \
    if (t == ((idx) >> 2)) {                                                   \
        if (_sel == 0) x0 = (val); else if (_sel == 1) x1 = (val);             \
        else if (_sel == 2) x2 = (val); else x3 = (val);                       \
    }                                                                          \
} while (0)

// set scan-guard for column idx on its owner lane
#define SET_GUARD(idx) do {                                                    \
    if (t == ((idx) >> 2)) {                                                   \
        const int _s = (idx) & 3;                                              \
        if (_s == 0) g0 = 0x7FFFFFFF; else if (_s == 1) g1 = 0x7FFFFFFF;       \
        else if (_s == 2) g2 = 0x7FFFFFFF; else g3 = 0x7FFFFFFF;               \
    }                                                                          \
} while (0)

// integer relax of one staged row. addv = (biased minVal) - KBIAS - u[row]
// for tree rows, or -u[row] for sources (distance 0). vnK = KBIAS - v.
// Scanned cols self-freeze: new dist >= popped dist (Dijkstra order).
#define RELAX(hh, addv, predrow) do {                                          \
    int r_, kn_;                                                               \
    r_  = (addv) + lo16((hh).x) + vn0;                                         \
    kn_ = (r_ << 8) | c0i; if (kn_ < k0) { p0 = (predrow); k0 = kn_; }         \
    r_  = (addv) + hi16((hh).x) + vn1;                                         \
    kn_ = (r_ << 8) | c1i; if (kn_ < k1) { p1 = (predrow); k1 = kn_; }         \
    r_  = (addv) + lo16((hh).y) + vn2;                                         \
    kn_ = (r_ << 8) | c2i; if (kn_ < k2) { p2 = (predrow); k2 = kn_; }         \
    r_  = (addv) + hi16((hh).y) + vn3;                                         \
    kn_ = (r_ << 8) | c3i; if (kn_ < k3) { p3 = (predrow); k3 = kn_; }         \
} while (0)

__device__ __forceinline__ int lo16(int p) { return (int)(short)(p & 0xFFFF); }
__device__ __forceinline__ int hi16(int p) { return p >> 16; }

// One block = one wave = one batch element.
// JV LAP in i32 FIXED-POINT (scale 2^12) on i16-packed costs staged in LDS:
//   1) column reduction + greedy init
//   2) exact-bid auction passes (stalls quickly; first passes are free wins)
//   3) MULTI-SOURCE shortest augmenting path: every remaining free row is a
//      distance-0 source (super-source SAP). One augmentation per search; the
//      reached source is found by walking path[] back to a row with
//      col4row == -1. All free rows get u += minVal (standard super-source
//      dual update; keeps duals feasible, matched edges tight). Keys carry a
//      +2^20 bias (folded into vn) so stale-u negative distances still sort
//      correctly under unsigned min.
// Result: exact optimum of the quantized matrix. Gather uses ORIGINAL f32.
__global__ __launch_bounds__(BS) void lap_kernel(const float* __restrict__ Dm,
                                                 double* __restrict__ batch_sums) {
    const int b = blockIdx.x;
    const int t = threadIdx.x;  // 0..63
    const float* __restrict__ cost = Dm + (size_t)b * N_DIM * N_DIM;
    const float4* __restrict__ cost4 = (const float4*)cost;

    __shared__ int2     chi[N_DIM * BS];    // [row][lane]: 4 i16 costs, 128 KB
    __shared__ int      u_s[N_DIM];
    __shared__ int      v_s[N_DIM];
    __shared__ int      row4col_s[N_DIM];
    __shared__ int      col4row_s[N_DIM];
    __shared__ int      queue_s[N_DIM];     // doubles as rowcand during greedy
    __shared__ unsigned bid_s[N_DIM];
    __shared__ int      qcnt_s;

    const int c0i = 4 * t, c1i = 4 * t + 1, c2i = 4 * t + 2, c3i = 4 * t + 3;

    // ---- stage i16 matrix + column reduction on QUANTIZED values ----
    int cmn0 = INT_MAX, cmn1 = INT_MAX, cmn2 = INT_MAX, cmn3 = INT_MAX;
    int ca0 = 0, ca1 = 0, ca2 = 0, ca3 = 0;
    for (int r = 0; r < N_DIM; ++r) {
        const float4 c4 = cost4[r * BS + t];
        const int a0 = __float2int_rn(c4.x * SCALE);
        const int a1 = __float2int_rn(c4.y * SCALE);
        const int a2 = __float2int_rn(c4.z * SCALE);
        const int a3 = __float2int_rn(c4.w * SCALE);
        int2 p;
        p.x = (a0 & 0xFFFF) | (a1 << 16);
        p.y = (a2 & 0xFFFF) | (a3 << 16);
        chi[r * BS + t] = p;
        if (a0 < cmn0) { cmn0 = a0; ca0 = r; }
        if (a1 < cmn1) { cmn1 = a1; ca1 = r; }
        if (a2 < cmn2) { cmn2 = a2; ca2 = r; }
        if (a3 < cmn3) { cmn3 = a3; ca3 = r; }
    }
    {
        int4 vv; vv.x = cmn0; vv.y = cmn1; vv.z = cmn2; vv.w = cmn3;
        ((int4*)v_s)[t] = vv;
        int4 zz; zz.x = 0; zz.y = 0; zz.z = 0; zz.w = 0;
        ((int4*)u_s)[t] = zz;
        int4 mm; mm.x = -1; mm.y = -1; mm.z = -1; mm.w = -1;
        ((int4*)row4col_s)[t] = mm;
        ((int4*)col4row_s)[t] = mm;
        int4 rc; rc.x = 0x7fffffff; rc.y = 0x7fffffff; rc.z = 0x7fffffff; rc.w = 0x7fffffff;
        ((int4*)queue_s)[t] = rc;   // rowcand
        uint4 bb; bb.x = ~0u; bb.y = ~0u; bb.z = ~0u; bb.w = ~0u;
        ((uint4*)bid_s)[t] = bb;
    }
    __syncthreads();
    // greedy: each candidate row goes to the lowest claiming column
    atomicMin(&queue_s[ca0], c0i);
    atomicMin(&queue_s[ca1], c1i);
    atomicMin(&queue_s[ca2], c2i);
    atomicMin(&queue_s[ca3], c3i);
    __syncthreads();
    if (queue_s[ca0] == c0i) { row4col_s[c0i] = ca0; col4row_s[ca0] = c0i; }
    if (queue_s[ca1] == c1i) { row4col_s[c1i] = ca1; col4row_s[ca1] = c1i; }
    if (queue_s[ca2] == c2i) { row4col_s[c2i] = ca2; col4row_s[ca2] = c2i; }
    if (queue_s[ca3] == c3i) { row4col_s[c3i] = ca3; col4row_s[ca3] = c3i; }
    __syncthreads();

    // ---- exact-bid auction passes (matched edges stay TIGHT) ----
    for (int pass = 0; pass < 12; ++pass) {
        if (t == 0) qcnt_s = 0;
        __syncthreads();
        {
            const int4 my = ((const int4*)col4row_s)[t];
            const int nf = (my.x < 0) + (my.y < 0) + (my.z < 0) + (my.w < 0);
            if (nf) {
                int pos = atomicAdd(&qcnt_s, nf);
                if (my.x < 0) queue_s[pos++] = c0i;
                if (my.y < 0) queue_s[pos++] = c1i;
                if (my.z < 0) queue_s[pos++] = c2i;
                if (my.w < 0) queue_s[pos++] = c3i;
            }
        }
        __syncthreads();
        const int n = qcnt_s;
        if (n == 0) break;
        for (int base = 0; base < n; base += BS) {
            const int my_row = (base + t < n) ? queue_s[base + t] : -1;
            int d1 = INT_MAX, d2 = INT_MAX;
            int j1 = 0;
            if (my_row >= 0) {
                const int rb = my_row * BS;
                for (int l = 0; l < BS; ++l) {
                    const int l2 = (l + t) & 63;  // rotate start: avoid bank pileup
                    const int2 h = chi[rb + l2];
                    const int4 vv = ((const int4*)v_s)[l2];
                    int d;
                    d = lo16(h.x) - vv.x; if (d < d1) { d2 = d1; d1 = d; j1 = 4 * l2 + 0; } else if (d < d2) d2 = d;
                    d = hi16(h.x) - vv.y; if (d < d1) { d2 = d1; d1 = d; j1 = 4 * l2 + 1; } else if (d < d2) d2 = d;
                    d = lo16(h.y) - vv.z; if (d < d1) { d2 = d1; d1 = d; j1 = 4 * l2 + 2; } else if (d < d2) d2 = d;
                    d = hi16(h.y) - vv.w; if (d < d1) { d2 = d1; d1 = d; j1 = 4 * l2 + 3; } else if (d < d2) d2 = d;
                }
                atomicMin(&bid_s[j1], ((unsigned)d1 << 8) | (unsigned)t);
            }
            __syncthreads();
            if (my_row >= 0) {
                const unsigned mybid = ((unsigned)d1 << 8) | (unsigned)t;
                if (bid_s[j1] == mybid) {  // unique winner per column
                    const int i0 = row4col_s[j1];
                    row4col_s[j1] = my_row;
                    col4row_s[my_row] = j1;
                    if (i0 >= 0) col4row_s[i0] = -1;
                    u_s[my_row] = d2;
                    v_s[j1] += d1 - d2;    // exact: matched edge tight, duals feasible
                    bid_s[j1] = ~0u;       // reset for next round
                }
            }
            __syncthreads();
        }
    }

    // ---- refresh register state from LDS (vn carries the key bias) ----
    const int4 vv4 = ((const int4*)v_s)[t];
    int vn0 = KBIAS - vv4.x, vn1 = KBIAS - vv4.y;
    int vn2 = KBIAS - vv4.z, vn3 = KBIAS - vv4.w;
    const int4 m4 = ((const int4*)row4col_s)[t];
    int r4c0 = m4.x, r4c1 = m4.y, r4c2 = m4.z, r4c3 = m4.w;
    const int4 y4 = ((const int4*)col4row_s)[t];
    int c4r0 = y4.x, c4r1 = y4.y, c4r2 = y4.z, c4r3 = y4.w;
    int p0 = 0, p1 = 0, p2 = 0, p3 = 0;

    unsigned long long fm0 = __ballot(c4r0 < 0);
    unsigned long long fm1 = __ballot(c4r1 < 0);
    unsigned long long fm2 = __ballot(c4r2 < 0);
    unsigned long long fm3 = __ballot(c4r3 < 0);

    const int KINIT0 = (0x7FFFFF << 8) | c0i;
    const int KINIT1 = (0x7FFFFF << 8) | c1i;
    const int KINIT2 = (0x7FFFFF << 8) | c2i;
    const int KINIT3 = (0x7FFFFF << 8) | c3i;

    // ---- multi-source shortest augmenting path ----
    while (fm0 | fm1 | fm2 | fm3) {
        int k0 = KINIT0, k1 = KINIT1, k2 = KINIT2, k3 = KINIT3;  // biased keys
        int g0 = 0, g1 = 0, g2 = 0, g3 = 0;                      // scan guards
        int minValB = 0;
        int sink = -1;

        // prologue: relax ALL free rows as distance-0 sources
        {
            unsigned long long s0 = fm0, s1 = fm1, s2 = fm2, s3 = fm3;
            while (s0 | s1 | s2 | s3) {
                int i;
                if (s0)      { const int tt = __builtin_ctzll(s0); s0 &= s0 - 1; i = tt * 4 + 0; }
                else if (s1) { const int tt = __builtin_ctzll(s1); s1 &= s1 - 1; i = tt * 4 + 1; }
                else if (s2) { const int tt = __builtin_ctzll(s2); s2 &= s2 - 1; i = tt * 4 + 2; }
                else         { const int tt = __builtin_ctzll(s3); s3 &= s3 - 1; i = tt * 4 + 3; }
                const int2 hS = chi[i * BS + t];
                const int  uS = u_s[i];
                RELAX(hS, -uS, i);
            }
        }

        // pop loop (single-pop, R8 structure)
        while (true) {
            const int q0 = k0 | g0, q1 = k1 | g1, q2 = k2 | g2, q3 = k3 | g3;
            const int q01 = (q0 < q1) ? q0 : q1;
            const int q23 = (q2 < q3) ? q2 : q3;
            const int gk = (int)wave_min_u32((unsigned)((q01 < q23) ? q01 : q23));

            const int bi = gk & 0xFF;
            minValB = gk >> 8;                                  // biased popped dist
            const int r4 = rd4_i(r4c0, r4c1, r4c2, r4c3, bi);   // matched row
            SET_GUARD(bi);
            if (r4 < 0) { sink = bi; break; }

            const int2 h   = chi[r4 * BS + t];   // ds_read_b64
            const int ucur = u_s[r4];            // uniform LDS read (parallel)
            RELAX(h, minValB - KBIAS - ucur, r4);
        }

        // dual update: scanned columns (guards) + u bump for ALL sources
        if (g0) { const int dv = minValB - (k0 >> 8); vn0 += dv; if (r4c0 >= 0) u_s[r4c0] += dv; }
        if (g1) { const int dv = minValB - (k1 >> 8); vn1 += dv; if (r4c1 >= 0) u_s[r4c1] += dv; }
        if (g2) { const int dv = minValB - (k2 >> 8); vn2 += dv; if (r4c2 >= 0) u_s[r4c2] += dv; }
        if (g3) { const int dv = minValB - (k3 >> 8); vn3 += dv; if (r4c3 >= 0) u_s[r4c3] += dv; }
        {
            const int mvt = minValB - KBIAS;  // true minVal
            if (c4r0 < 0) u_s[c0i] += mvt;
            if (c4r1 < 0) u_s[c1i] += mvt;
            if (c4r2 < 0) u_s[c2i] += mvt;
            if (c4r3 < 0) u_s[c3i] += mvt;
        }

        // augment: walk back until we hit a free (source) row; match it
        {
            int jj = sink;
            while (true) {
                const int ii = rd4_i(p0, p1, p2, p3, jj);
                SET4(r4c0, r4c1, r4c2, r4c3, jj, ii);
                const int tmp = rd4_i(c4r0, c4r1, c4r2, c4r3, ii);
                SET4(c4r0, c4r1, c4r2, c4r3, ii, jj);
                if (tmp < 0) {
                    // ii was a source row -- now matched; remove from free set
                    const int tt_ = ii >> 2, kk_ = ii & 3;
                    if (kk_ == 0) fm0 &= ~(1ull << tt_);
                    else if (kk_ == 1) fm1 &= ~(1ull << tt_);
                    else if (kk_ == 2) fm2 &= ~(1ull << tt_);
                    else fm3 &= ~(1ull << tt_);
                    break;
                }
                jj = tmp;
            }
        }
    }

    // ---- gather matched ORIGINAL f32 costs (4 rows per lane), reduce in f64 ----
    double s = 0.0;
    s += (double)cost[(size_t)(t * 4 + 0) * N_DIM + c4r0];
    s += (double)cost[(size_t)(t * 4 + 1) * N_DIM + c4r1];
    s += (double)cost[(size_t)(t * 4 + 2) * N_DIM + c4r2];
    s += (double)cost[(size_t)(t * 4 + 3) * N_DIM + c4r3];
    #pragma unroll
    for (int off = 32; off > 0; off >>= 1) s += __shfl_down(s, off);
    if (t == 0) batch_sums[b] = s;
}

__global__ void finalize_kernel(const double* __restrict__ batch_sums,
                                float* __restrict__ out) {
    const int t = threadIdx.x;  // 64 threads, one wave
    double s = batch_sums[t];
    #pragma unroll
    for (int off = 32; off > 0; off >>= 1) s += __shfl_down(s, off);
    if (t == 0) out[0] = (float)(s / (double)((long long)BATCH * N_DIM));
}

extern "C" void kernel_launch(void* const* d_in, const int* in_sizes, int n_in,
                              void* d_out, int out_size, void* d_ws, size_t ws_size,
                              hipStream_t stream) {
    const float* Dm = (const float*)d_in[0];
    float* out = (float*)d_out;
    double* sums = (double*)d_ws;  // 64 * 8 = 512 bytes

    lap_kernel<<<BATCH, BS, 0, stream>>>(Dm, sums);
    finalize_kernel<<<1, 64, 0, stream>>>(sums, out);
}

// Round 15
// 737.626 us; speedup vs baseline: 1.2393x; 1.2393x over previous
//
#include <hip/hip_runtime.h>

#define N_DIM 256
#define BATCH 64
#define BS 64          // one wave per block; lane t owns columns/rows 4t..4t+3
#define SCALE 4096.0f  // fixed-point scale 2^12

#define DPP_MINU(x, ctrl) do {                                                 \
    unsigned _s = (unsigned)__builtin_amdgcn_update_dpp((int)(x), (int)(x),    \
                                                        (ctrl), 0xf, 0xf, false); \
    (x) = ((x) < _s) ? (x) : _s;                                               \
} while (0)

// Hybrid full-wave u32 min: 4 DPP stages reduce within each 16-lane row
// (result in lanes 15/31/47/63), then 4 independent readlanes + scalar mins.
__device__ __forceinline__ unsigned wave_min_u32(unsigned x) {
    DPP_MINU(x, 0x111);  // row_shr:1
    DPP_MINU(x, 0x112);  // row_shr:2
    DPP_MINU(x, 0x114);  // row_shr:4
    DPP_MINU(x, 0x118);  // row_shr:8
    const unsigned a = (unsigned)__builtin_amdgcn_readlane((int)x, 15);
    const unsigned b = (unsigned)__builtin_amdgcn_readlane((int)x, 31);
    const unsigned c = (unsigned)__builtin_amdgcn_readlane((int)x, 47);
    const unsigned d = (unsigned)__builtin_amdgcn_readlane((int)x, 63);
    const unsigned ab = (a < b) ? a : b;
    const unsigned cd = (c < d) ? c : d;
    return (ab < cd) ? ab : cd;
}

// uniform-index lookup from 4 per-lane mirror regs: 2 selects + 1 readlane
__device__ __forceinline__ int rd4_i(int x0, int x1, int x2, int x3, int idx) {
    const int sel = idx & 3, src = idx >> 2;
    int ab = (sel & 1) ? x1 : x0;
    int cd = (sel & 1) ? x3 : x2;
    int vv = (sel & 2) ? cd : ab;
    return __builtin_amdgcn_readlane(vv, src);
}

// owner-lane mirror update (idx wave-uniform)
#define SET4(x0, x1, x2, x3, idx, val) do {                                    \
    const int _sel = (idx) & 3;                                                \
    if (t == ((idx) >> 2)) {                                                   \
        if (_sel == 0) x0 = (val); else if (_sel == 1) x1 = (val);             \
        else if (_sel == 2) x2 = (val); else x3 = (val);                       \
    }                                                                          \
} while (0)

__device__ __forceinline__ int lo16(int p) { return (int)(short)(p & 0xFFFF); }
__device__ __forceinline__ int hi16(int p) { return p >> 16; }

// One block = one wave = one batch element.
// JV LAP in i32 FIXED-POINT (scale 2^12) on i16-packed costs staged in LDS:
//   1) column reduction + greedy init
//   2) lane-parallel auction passes (exact bids; ghost-stall detected by a
//      3-pass no-decrease watchdog -> break early, saving dead scan passes)
//   3) shortest augmenting path (Dijkstra): integer keys (spc<<8|col),
//      guard regs for scanned cols, register mirrors, no inner barriers.
// Integer arithmetic is EXACT -> duals exactly feasible, result is the exact
// optimum of the quantized matrix. Final gather uses ORIGINAL f32 values.
__global__ __launch_bounds__(BS) void lap_kernel(const float* __restrict__ Dm,
                                                 double* __restrict__ batch_sums) {
    const int b = blockIdx.x;
    const int t = threadIdx.x;  // 0..63
    const float* __restrict__ cost = Dm + (size_t)b * N_DIM * N_DIM;
    const float4* __restrict__ cost4 = (const float4*)cost;

    __shared__ int2     chi[N_DIM * BS];    // [row][lane]: 4 i16 costs, 128 KB
    __shared__ int      u_s[N_DIM];
    __shared__ int      v_s[N_DIM];
    __shared__ int      row4col_s[N_DIM];
    __shared__ int      col4row_s[N_DIM];
    __shared__ int      queue_s[N_DIM];     // doubles as rowcand during greedy
    __shared__ unsigned bid_s[N_DIM];
    __shared__ int      qcnt_s;

    const int c0i = 4 * t, c1i = 4 * t + 1, c2i = 4 * t + 2, c3i = 4 * t + 3;

    // ---- stage i16 matrix + column reduction on QUANTIZED values ----
    int cmn0 = INT_MAX, cmn1 = INT_MAX, cmn2 = INT_MAX, cmn3 = INT_MAX;
    int ca0 = 0, ca1 = 0, ca2 = 0, ca3 = 0;
    for (int r = 0; r < N_DIM; ++r) {
        const float4 c4 = cost4[r * BS + t];
        const int a0 = __float2int_rn(c4.x * SCALE);
        const int a1 = __float2int_rn(c4.y * SCALE);
        const int a2 = __float2int_rn(c4.z * SCALE);
        const int a3 = __float2int_rn(c4.w * SCALE);
        int2 p;
        p.x = (a0 & 0xFFFF) | (a1 << 16);
        p.y = (a2 & 0xFFFF) | (a3 << 16);
        chi[r * BS + t] = p;
        if (a0 < cmn0) { cmn0 = a0; ca0 = r; }
        if (a1 < cmn1) { cmn1 = a1; ca1 = r; }
        if (a2 < cmn2) { cmn2 = a2; ca2 = r; }
        if (a3 < cmn3) { cmn3 = a3; ca3 = r; }
    }
    {
        int4 vv; vv.x = cmn0; vv.y = cmn1; vv.z = cmn2; vv.w = cmn3;
        ((int4*)v_s)[t] = vv;
        int4 zz; zz.x = 0; zz.y = 0; zz.z = 0; zz.w = 0;
        ((int4*)u_s)[t] = zz;
        int4 mm; mm.x = -1; mm.y = -1; mm.z = -1; mm.w = -1;
        ((int4*)row4col_s)[t] = mm;
        ((int4*)col4row_s)[t] = mm;
        int4 rc; rc.x = 0x7fffffff; rc.y = 0x7fffffff; rc.z = 0x7fffffff; rc.w = 0x7fffffff;
        ((int4*)queue_s)[t] = rc;   // rowcand
        uint4 bb; bb.x = ~0u; bb.y = ~0u; bb.z = ~0u; bb.w = ~0u;
        ((uint4*)bid_s)[t] = bb;
    }
    __syncthreads();
    // greedy: each candidate row goes to the lowest claiming column
    atomicMin(&queue_s[ca0], c0i);
    atomicMin(&queue_s[ca1], c1i);
    atomicMin(&queue_s[ca2], c2i);
    atomicMin(&queue_s[ca3], c3i);
    __syncthreads();
    if (queue_s[ca0] == c0i) { row4col_s[c0i] = ca0; col4row_s[ca0] = c0i; }
    if (queue_s[ca1] == c1i) { row4col_s[c1i] = ca1; col4row_s[ca1] = c1i; }
    if (queue_s[ca2] == c2i) { row4col_s[c2i] = ca2; col4row_s[ca2] = c2i; }
    if (queue_s[ca3] == c3i) { row4col_s[c3i] = ca3; col4row_s[ca3] = c3i; }
    __syncthreads();

    // ---- lane-parallel auction (exact bids) with stall watchdog ----
    int prev_n = 0x7fffffff;
    int stall  = 0;
    for (int pass = 0; pass < 24; ++pass) {
        if (t == 0) qcnt_s = 0;
        __syncthreads();
        {
            const int4 my = ((const int4*)col4row_s)[t];
            const int nf = (my.x < 0) + (my.y < 0) + (my.z < 0) + (my.w < 0);
            if (nf) {
                int pos = atomicAdd(&qcnt_s, nf);
                if (my.x < 0) queue_s[pos++] = c0i;
                if (my.y < 0) queue_s[pos++] = c1i;
                if (my.z < 0) queue_s[pos++] = c2i;
                if (my.w < 0) queue_s[pos++] = c3i;
            }
        }
        __syncthreads();
        const int n = qcnt_s;
        if (n == 0) break;
        // ghost-stall watchdog: exact-bid auctions stop decreasing n once all
        // queued rows are blocked by stale bids; dead passes only burn scans.
        if (n >= prev_n) { if (++stall >= 3) break; } else stall = 0;
        prev_n = n;
        for (int base = 0; base < n; base += BS) {
            const int my_row = (base + t < n) ? queue_s[base + t] : -1;
            int d1 = INT_MAX, d2 = INT_MAX;
            int j1 = 0;
            if (my_row >= 0) {
                const int rb = my_row * BS;
                for (int l = 0; l < BS; ++l) {
                    const int l2 = (l + t) & 63;  // rotate start: avoid bank pileup
                    const int2 h = chi[rb + l2];
                    const int4 vv = ((const int4*)v_s)[l2];
                    int d;
                    d = lo16(h.x) - vv.x; if (d < d1) { d2 = d1; d1 = d; j1 = 4 * l2 + 0; } else if (d < d2) d2 = d;
                    d = hi16(h.x) - vv.y; if (d < d1) { d2 = d1; d1 = d; j1 = 4 * l2 + 1; } else if (d < d2) d2 = d;
                    d = lo16(h.y) - vv.z; if (d < d1) { d2 = d1; d1 = d; j1 = 4 * l2 + 2; } else if (d < d2) d2 = d;
                    d = hi16(h.y) - vv.w; if (d < d1) { d2 = d1; d1 = d; j1 = 4 * l2 + 3; } else if (d < d2) d2 = d;
                }
                atomicMin(&bid_s[j1], ((unsigned)d1 << 8) | (unsigned)t);
            }
            __syncthreads();
            if (my_row >= 0) {
                const unsigned mybid = ((unsigned)d1 << 8) | (unsigned)t;
                if (bid_s[j1] == mybid) {  // unique winner per column
                    const int i0 = row4col_s[j1];
                    row4col_s[j1] = my_row;
                    col4row_s[my_row] = j1;
                    if (i0 >= 0) col4row_s[i0] = -1;
                    u_s[my_row] = d2;
                    v_s[j1] += d1 - d2;    // v only decreases -> duals stay feasible
                    bid_s[j1] = ~0u;       // reset for next round
                }
            }
            __syncthreads();
        }
    }

    // ---- refresh register state from LDS ----
    const int4 vv4 = ((const int4*)v_s)[t];
    int vn0 = -vv4.x, vn1 = -vv4.y, vn2 = -vv4.z, vn3 = -vv4.w;  // negated duals
    const int4 m4 = ((const int4*)row4col_s)[t];
    int r4c0 = m4.x, r4c1 = m4.y, r4c2 = m4.z, r4c3 = m4.w;
    const int4 y4 = ((const int4*)col4row_s)[t];
    int c4r0 = y4.x, c4r1 = y4.y, c4r2 = y4.z, c4r3 = y4.w;
    int p0 = 0, p1 = 0, p2 = 0, p3 = 0;

    unsigned long long fm0 = __ballot(c4r0 < 0);
    unsigned long long fm1 = __ballot(c4r1 < 0);
    unsigned long long fm2 = __ballot(c4r2 < 0);
    unsigned long long fm3 = __ballot(c4r3 < 0);

    const int KINIT0 = (0x7FFFFF << 8) | c0i;
    const int KINIT1 = (0x7FFFFF << 8) | c1i;
    const int KINIT2 = (0x7FFFFF << 8) | c2i;
    const int KINIT3 = (0x7FFFFF << 8) | c3i;

    // ---- shortest augmenting path per remaining free row ----
    while (fm0 | fm1 | fm2 | fm3) {
        int i;
        if (fm0)      { const int tt = __builtin_ctzll(fm0); fm0 &= fm0 - 1; i = tt * 4 + 0; }
        else if (fm1) { const int tt = __builtin_ctzll(fm1); fm1 &= fm1 - 1; i = tt * 4 + 1; }
        else if (fm2) { const int tt = __builtin_ctzll(fm2); fm2 &= fm2 - 1; i = tt * 4 + 2; }
        else          { const int tt = __builtin_ctzll(fm3); fm3 &= fm3 - 1; i = tt * 4 + 3; }

        int k0 = KINIT0, k1 = KINIT1, k2 = KINIT2, k3 = KINIT3;  // (spc<<8)|col
        int g0 = 0, g1 = 0, g2 = 0, g3 = 0;                      // scan guards
        int cur = i;
        int minVal = 0;
        int sink = -1;

        while (true) {
            const int2 h   = chi[cur * BS + t];   // ds_read_b64
            const int ucur = u_s[cur];            // uniform LDS read (parallel)
            const int add  = minVal - ucur;

            // integer relax; monotone for scanned cols (r >= minVal >= spc)
            int r, kn;
            r  = add + lo16(h.x) + vn0;
            kn = (r << 8) | c0i; if (kn < k0) { p0 = cur; k0 = kn; }
            r  = add + hi16(h.x) + vn1;
            kn = (r << 8) | c1i; if (kn < k1) { p1 = cur; k1 = kn; }
            r  = add + lo16(h.y) + vn2;
            kn = (r << 8) | c2i; if (kn < k2) { p2 = cur; k2 = kn; }
            r  = add + hi16(h.y) + vn3;
            kn = (r << 8) | c3i; if (kn < k3) { p3 = cur; k3 = kn; }

            // guarded argmin (scanned cols masked to INT_MAX via OR)
            const int q0 = k0 | g0, q1 = k1 | g1, q2 = k2 | g2, q3 = k3 | g3;
            int q01 = (q0 < q1) ? q0 : q1;
            int q23 = (q2 < q3) ? q2 : q3;
            const int gk = (int)wave_min_u32((unsigned)((q01 < q23) ? q01 : q23));

            const int bi = gk & 0xFF;
            minVal = gk >> 8;                                   // exact spc of pop
            const int r4 = rd4_i(r4c0, r4c1, r4c2, r4c3, bi);   // matched row
            if (t == (bi >> 2)) {
                const int s = bi & 3;
                if (s == 0) g0 = 0x7FFFFFFF; else if (s == 1) g1 = 0x7FFFFFFF;
                else if (s == 2) g2 = 0x7FFFFFFF; else g3 = 0x7FFFFFFF;
            }
            if (r4 < 0) { sink = bi; break; }
            cur = r4;
        }

        // dual update (guards mark scanned; matched rows distinct across cols)
        if (g0) { const int dv = minVal - (k0 >> 8); vn0 += dv; if (r4c0 >= 0) u_s[r4c0] += dv; }
        if (g1) { const int dv = minVal - (k1 >> 8); vn1 += dv; if (r4c1 >= 0) u_s[r4c1] += dv; }
        if (g2) { const int dv = minVal - (k2 >> 8); vn2 += dv; if (r4c2 >= 0) u_s[r4c2] += dv; }
        if (g3) { const int dv = minVal - (k3 >> 8); vn3 += dv; if (r4c3 >= 0) u_s[r4c3] += dv; }
        if (t == 0) u_s[i] += minVal;

        // augment alternating path (uniform walk over register mirrors)
        if (sink >= 0) {
            int jj = sink;
            while (true) {
                const int ii = rd4_i(p0, p1, p2, p3, jj);
                SET4(r4c0, r4c1, r4c2, r4c3, jj, ii);
                const int tmp = rd4_i(c4r0, c4r1, c4r2, c4r3, ii);
                SET4(c4r0, c4r1, c4r2, c4r3, ii, jj);
                jj = tmp;
                if (ii == i) break;
            }
        }
    }

    // ---- gather matched ORIGINAL f32 costs (4 rows per lane), reduce in f64 ----
    double s = 0.0;
    s += (double)cost[(size_t)(t * 4 + 0) * N_DIM + c4r0];
    s += (double)cost[(size_t)(t * 4 + 1) * N_DIM + c4r1];
    s += (double)cost[(size_t)(t * 4 + 2) * N_DIM + c4r2];
    s += (double)cost[(size_t)(t * 4 + 3) * N_DIM + c4r3];
    #pragma unroll
    for (int off = 32; off > 0; off >>= 1) s += __shfl_down(s, off);
    if (t == 0) batch_sums[b] = s;
}

__global__ void finalize_kernel(const double* __restrict__ batch_sums,
                                float* __restrict__ out) {
    const int t = threadIdx.x;  // 64 threads, one wave
    double s = batch_sums[t];
    #pragma unroll
    for (int off = 32; off > 0; off >>= 1) s += __shfl_down(s, off);
    if (t == 0) out[0] = (float)(s / (double)((long long)BATCH * N_DIM));
}

extern "C" void kernel_launch(void* const* d_in, const int* in_sizes, int n_in,
                              void* d_out, int out_size, void* d_ws, size_t ws_size,
                              hipStream_t stream) {
    const float* Dm = (const float*)d_in[0];
    float* out = (float*)d_out;
    double* sums = (double*)d_ws;  // 64 * 8 = 512 bytes

    lap_kernel<<<BATCH, BS, 0, stream>>>(Dm, sums);
    finalize_kernel<<<1, 64, 0, stream>>>(sums, out);
}

// Round 16
// 725.378 us; speedup vs baseline: 1.2602x; 1.0169x over previous
//
#include <hip/hip_runtime.h>

#define N_DIM 256
#define BATCH 64
#define BS 64          // one wave per block; lane t owns columns/rows 4t..4t+3
#define SCALE 4096.0f  // fixed-point scale 2^12

#define DPP_MINU(x, ctrl) do {                                                 \
    unsigned _s = (unsigned)__builtin_amdgcn_update_dpp((int)(x), (int)(x),    \
                                                        (ctrl), 0xf, 0xf, false); \
    (x) = ((x) < _s) ? (x) : _s;                                               \
} while (0)

// Hybrid full-wave u32 min: 4 DPP stages reduce within each 16-lane row
// (result in lanes 15/31/47/63), then 4 independent readlanes + scalar mins.
// Shorter dependent chain than 6 DPP stages, and the result is SGPR-uniform.
__device__ __forceinline__ unsigned wave_min_u32(unsigned x) {
    DPP_MINU(x, 0x111);  // row_shr:1
    DPP_MINU(x, 0x112);  // row_shr:2
    DPP_MINU(x, 0x114);  // row_shr:4
    DPP_MINU(x, 0x118);  // row_shr:8
    const unsigned a = (unsigned)__builtin_amdgcn_readlane((int)x, 15);
    const unsigned b = (unsigned)__builtin_amdgcn_readlane((int)x, 31);
    const unsigned c = (unsigned)__builtin_amdgcn_readlane((int)x, 47);
    const unsigned d = (unsigned)__builtin_amdgcn_readlane((int)x, 63);
    const unsigned ab = (a < b) ? a : b;
    const unsigned cd = (c < d) ? c : d;
    return (ab < cd) ? ab : cd;
}

// uniform-index lookup from 4 per-lane mirror regs: 2 selects + 1 readlane
__device__ __forceinline__ int rd4_i(int x0, int x1, int x2, int x3, int idx) {
    const int sel = idx & 3, src = idx >> 2;
    int ab = (sel & 1) ? x1 : x0;
    int cd = (sel & 1) ? x3 : x2;
    int vv = (sel & 2) ? cd : ab;
    return __builtin_amdgcn_readlane(vv, src);
}

// owner-lane mirror update (idx wave-uniform)
#define SET4(x0, x1, x2, x3, idx, val) do {                                    \
    const int _sel = (idx) & 3;                                                \
    if (t == ((idx) >> 2)) {                                                   \
        if (_sel == 0) x0 = (val); else if (_sel == 1) x1 = (val);             \
        else if (_sel == 2) x2 = (val); else x3 = (val);                       \
    }                                                                          \
} while (0)

__device__ __forceinline__ int lo16(int p) { return (int)(short)(p & 0xFFFF); }
__device__ __forceinline__ int hi16(int p) { return p >> 16; }

// One block = one wave = one batch element.
// JV LAP in i32 FIXED-POINT (scale 2^12) on i16-packed costs staged in LDS:
//   1) column reduction + greedy init
//   2) lane-parallel augmenting row reduction (auction bids, 24 passes,
//      full-queue chunking)
//   3) shortest augmenting path (Dijkstra): integer keys (spc<<8|col),
//      guard regs for scanned cols, register mirrors, no inner barriers.
// Integer arithmetic is EXACT -> duals exactly feasible, result is the exact
// optimum of the quantized matrix. Final gather uses ORIGINAL f32 values.
__global__ __launch_bounds__(BS) void lap_kernel(const float* __restrict__ Dm,
                                                 double* __restrict__ batch_sums) {
    const int b = blockIdx.x;
    const int t = threadIdx.x;  // 0..63
    const float* __restrict__ cost = Dm + (size_t)b * N_DIM * N_DIM;
    const float4* __restrict__ cost4 = (const float4*)cost;

    __shared__ int2     chi[N_DIM * BS];    // [row][lane]: 4 i16 costs, 128 KB
    __shared__ int      u_s[N_DIM];
    __shared__ int      v_s[N_DIM];
    __shared__ int      row4col_s[N_DIM];
    __shared__ int      col4row_s[N_DIM];
    __shared__ int      queue_s[N_DIM];     // doubles as rowcand during greedy
    __shared__ unsigned bid_s[N_DIM];
    __shared__ int      qcnt_s;

    const int c0i = 4 * t, c1i = 4 * t + 1, c2i = 4 * t + 2, c3i = 4 * t + 3;

    // ---- stage i16 matrix + column reduction on QUANTIZED values ----
    int cmn0 = INT_MAX, cmn1 = INT_MAX, cmn2 = INT_MAX, cmn3 = INT_MAX;
    int ca0 = 0, ca1 = 0, ca2 = 0, ca3 = 0;
    for (int r = 0; r < N_DIM; ++r) {
        const float4 c4 = cost4[r * BS + t];
        const int a0 = __float2int_rn(c4.x * SCALE);
        const int a1 = __float2int_rn(c4.y * SCALE);
        const int a2 = __float2int_rn(c4.z * SCALE);
        const int a3 = __float2int_rn(c4.w * SCALE);
        int2 p;
        p.x = (a0 & 0xFFFF) | (a1 << 16);
        p.y = (a2 & 0xFFFF) | (a3 << 16);
        chi[r * BS + t] = p;
        if (a0 < cmn0) { cmn0 = a0; ca0 = r; }
        if (a1 < cmn1) { cmn1 = a1; ca1 = r; }
        if (a2 < cmn2) { cmn2 = a2; ca2 = r; }
        if (a3 < cmn3) { cmn3 = a3; ca3 = r; }
    }
    {
        int4 vv; vv.x = cmn0; vv.y = cmn1; vv.z = cmn2; vv.w = cmn3;
        ((int4*)v_s)[t] = vv;
        int4 zz; zz.x = 0; zz.y = 0; zz.z = 0; zz.w = 0;
        ((int4*)u_s)[t] = zz;
        int4 mm; mm.x = -1; mm.y = -1; mm.z = -1; mm.w = -1;
        ((int4*)row4col_s)[t] = mm;
        ((int4*)col4row_s)[t] = mm;
        int4 rc; rc.x = 0x7fffffff; rc.y = 0x7fffffff; rc.z = 0x7fffffff; rc.w = 0x7fffffff;
        ((int4*)queue_s)[t] = rc;   // rowcand
        uint4 bb; bb.x = ~0u; bb.y = ~0u; bb.z = ~0u; bb.w = ~0u;
        ((uint4*)bid_s)[t] = bb;
    }
    __syncthreads();
    // greedy: each candidate row goes to the lowest claiming column
    atomicMin(&queue_s[ca0], c0i);
    atomicMin(&queue_s[ca1], c1i);
    atomicMin(&queue_s[ca2], c2i);
    atomicMin(&queue_s[ca3], c3i);
    __syncthreads();
    if (queue_s[ca0] == c0i) { row4col_s[c0i] = ca0; col4row_s[ca0] = c0i; }
    if (queue_s[ca1] == c1i) { row4col_s[c1i] = ca1; col4row_s[ca1] = c1i; }
    if (queue_s[ca2] == c2i) { row4col_s[c2i] = ca2; col4row_s[ca2] = c2i; }
    if (queue_s[ca3] == c3i) { row4col_s[c3i] = ca3; col4row_s[ca3] = c3i; }
    __syncthreads();

    // ---- lane-parallel augmenting row reduction (auction, full-queue) ----
    for (int pass = 0; pass < 24; ++pass) {
        if (t == 0) qcnt_s = 0;
        __syncthreads();
        {
            const int4 my = ((const int4*)col4row_s)[t];
            const int nf = (my.x < 0) + (my.y < 0) + (my.z < 0) + (my.w < 0);
            if (nf) {
                int pos = atomicAdd(&qcnt_s, nf);
                if (my.x < 0) queue_s[pos++] = c0i;
                if (my.y < 0) queue_s[pos++] = c1i;
                if (my.z < 0) queue_s[pos++] = c2i;
                if (my.w < 0) queue_s[pos++] = c3i;
            }
        }
        __syncthreads();
        const int n = qcnt_s;
        if (n == 0) break;
        for (int base = 0; base < n; base += BS) {
            const int my_row = (base + t < n) ? queue_s[base + t] : -1;
            int d1 = INT_MAX, d2 = INT_MAX;
            int j1 = 0;
            if (my_row >= 0) {
                const int rb = my_row * BS;
                for (int l = 0; l < BS; ++l) {
                    const int l2 = (l + t) & 63;  // rotate start: avoid bank pileup
                    const int2 h = chi[rb + l2];
                    const int4 vv = ((const int4*)v_s)[l2];
                    int d;
                    d = lo16(h.x) - vv.x; if (d < d1) { d2 = d1; d1 = d; j1 = 4 * l2 + 0; } else if (d < d2) d2 = d;
                    d = hi16(h.x) - vv.y; if (d < d1) { d2 = d1; d1 = d; j1 = 4 * l2 + 1; } else if (d < d2) d2 = d;
                    d = lo16(h.y) - vv.z; if (d < d1) { d2 = d1; d1 = d; j1 = 4 * l2 + 2; } else if (d < d2) d2 = d;
                    d = hi16(h.y) - vv.w; if (d < d1) { d2 = d1; d1 = d; j1 = 4 * l2 + 3; } else if (d < d2) d2 = d;
                }
                atomicMin(&bid_s[j1], ((unsigned)d1 << 8) | (unsigned)t);
            }
            __syncthreads();
            if (my_row >= 0) {
                const unsigned mybid = ((unsigned)d1 << 8) | (unsigned)t;
                if (bid_s[j1] == mybid) {  // unique winner per column
                    const int i0 = row4col_s[j1];
                    row4col_s[j1] = my_row;
                    col4row_s[my_row] = j1;
                    if (i0 >= 0) col4row_s[i0] = -1;
                    u_s[my_row] = d2;
                    v_s[j1] += d1 - d2;    // v only decreases -> duals stay feasible
                    bid_s[j1] = ~0u;       // reset for next round
                }
            }
            __syncthreads();
        }
    }

    // ---- refresh register state from LDS ----
    const int4 vv4 = ((const int4*)v_s)[t];
    int vn0 = -vv4.x, vn1 = -vv4.y, vn2 = -vv4.z, vn3 = -vv4.w;  // negated duals
    const int4 m4 = ((const int4*)row4col_s)[t];
    int r4c0 = m4.x, r4c1 = m4.y, r4c2 = m4.z, r4c3 = m4.w;
    const int4 y4 = ((const int4*)col4row_s)[t];
    int c4r0 = y4.x, c4r1 = y4.y, c4r2 = y4.z, c4r3 = y4.w;
    int p0 = 0, p1 = 0, p2 = 0, p3 = 0;

    unsigned long long fm0 = __ballot(c4r0 < 0);
    unsigned long long fm1 = __ballot(c4r1 < 0);
    unsigned long long fm2 = __ballot(c4r2 < 0);
    unsigned long long fm3 = __ballot(c4r3 < 0);

    const int KINIT0 = (0x7FFFFF << 8) | c0i;
    const int KINIT1 = (0x7FFFFF << 8) | c1i;
    const int KINIT2 = (0x7FFFFF << 8) | c2i;
    const int KINIT3 = (0x7FFFFF << 8) | c3i;

    // ---- shortest augmenting path per remaining free row ----
    while (fm0 | fm1 | fm2 | fm3) {
        int i;
        if (fm0)      { const int tt = __builtin_ctzll(fm0); fm0 &= fm0 - 1; i = tt * 4 + 0; }
        else if (fm1) { const int tt = __builtin_ctzll(fm1); fm1 &= fm1 - 1; i = tt * 4 + 1; }
        else if (fm2) { const int tt = __builtin_ctzll(fm2); fm2 &= fm2 - 1; i = tt * 4 + 2; }
        else          { const int tt = __builtin_ctzll(fm3); fm3 &= fm3 - 1; i = tt * 4 + 3; }

        int k0 = KINIT0, k1 = KINIT1, k2 = KINIT2, k3 = KINIT3;  // (spc<<8)|col
        int g0 = 0, g1 = 0, g2 = 0, g3 = 0;                      // scan guards
        int cur = i;
        int minVal = 0;
        int sink = -1;

        while (true) {
            const int2 h   = chi[cur * BS + t];   // ds_read_b64
            const int ucur = u_s[cur];            // uniform LDS read (parallel)
            const int add  = minVal - ucur;

            // integer relax; monotone for scanned cols (r >= minVal >= spc)
            int r, kn;
            r  = add + lo16(h.x) + vn0;
            kn = (r << 8) | c0i; if (kn < k0) { p0 = cur; k0 = kn; }
            r  = add + hi16(h.x) + vn1;
            kn = (r << 8) | c1i; if (kn < k1) { p1 = cur; k1 = kn; }
            r  = add + lo16(h.y) + vn2;
            kn = (r << 8) | c2i; if (kn < k2) { p2 = cur; k2 = kn; }
            r  = add + hi16(h.y) + vn3;
            kn = (r << 8) | c3i; if (kn < k3) { p3 = cur; k3 = kn; }

            // guarded argmin (scanned cols masked to INT_MAX via OR)
            const int q0 = k0 | g0, q1 = k1 | g1, q2 = k2 | g2, q3 = k3 | g3;
            int q01 = (q0 < q1) ? q0 : q1;
            int q23 = (q2 < q3) ? q2 : q3;
            const int gk = (int)wave_min_u32((unsigned)((q01 < q23) ? q01 : q23));

            const int bi = gk & 0xFF;
            minVal = gk >> 8;                                   // exact spc of pop
            const int r4 = rd4_i(r4c0, r4c1, r4c2, r4c3, bi);   // matched row
            if (t == (bi >> 2)) {
                const int s = bi & 3;
                if (s == 0) g0 = 0x7FFFFFFF; else if (s == 1) g1 = 0x7FFFFFFF;
                else if (s == 2) g2 = 0x7FFFFFFF; else g3 = 0x7FFFFFFF;
            }
            if (r4 < 0) { sink = bi; break; }
            cur = r4;
        }

        // dual update (guards mark scanned; matched rows distinct across cols)
        if (g0) { const int dv = minVal - (k0 >> 8); vn0 += dv; if (r4c0 >= 0) u_s[r4c0] += dv; }
        if (g1) { const int dv = minVal - (k1 >> 8); vn1 += dv; if (r4c1 >= 0) u_s[r4c1] += dv; }
        if (g2) { const int dv = minVal - (k2 >> 8); vn2 += dv; if (r4c2 >= 0) u_s[r4c2] += dv; }
        if (g3) { const int dv = minVal - (k3 >> 8); vn3 += dv; if (r4c3 >= 0) u_s[r4c3] += dv; }
        if (t == 0) u_s[i] += minVal;

        // augment alternating path (uniform walk over register mirrors)
        if (sink >= 0) {
            int jj = sink;
            while (true) {
                const int ii = rd4_i(p0, p1, p2, p3, jj);
                SET4(r4c0, r4c1, r4c2, r4c3, jj, ii);
                const int tmp = rd4_i(c4r0, c4r1, c4r2, c4r3, ii);
                SET4(c4r0, c4r1, c4r2, c4r3, ii, jj);
                jj = tmp;
                if (ii == i) break;
            }
        }
    }

    // ---- gather matched ORIGINAL f32 costs (4 rows per lane), reduce in f64 ----
    double s = 0.0;
    s += (double)cost[(size_t)(t * 4 + 0) * N_DIM + c4r0];
    s += (double)cost[(size_t)(t * 4 + 1) * N_DIM + c4r1];
    s += (double)cost[(size_t)(t * 4 + 2) * N_DIM + c4r2];
    s += (double)cost[(size_t)(t * 4 + 3) * N_DIM + c4r3];
    #pragma unroll
    for (int off = 32; off > 0; off >>= 1) s += __shfl_down(s, off);
    if (t == 0) batch_sums[b] = s;
}

__global__ void finalize_kernel(const double* __restrict__ batch_sums,
                                float* __restrict__ out) {
    const int t = threadIdx.x;  // 64 threads, one wave
    double s = batch_sums[t];
    #pragma unroll
    for (int off = 32; off > 0; off >>= 1) s += __shfl_down(s, off);
    if (t == 0) out[0] = (float)(s / (double)((long long)BATCH * N_DIM));
}

extern "C" void kernel_launch(void* const* d_in, const int* in_sizes, int n_in,
                              void* d_out, int out_size, void* d_ws, size_t ws_size,
                              hipStream_t stream) {
    const float* Dm = (const float*)d_in[0];
    float* out = (float*)d_out;
    double* sums = (double*)d_ws;  // 64 * 8 = 512 bytes

    lap_kernel<<<BATCH, BS, 0, stream>>>(Dm, sums);
    finalize_kernel<<<1, 64, 0, stream>>>(sums, out);
}